// Round 11
// baseline (43.150 us; speedup 1.0000x reference)
//
#include <hip/hip_runtime.h>
#include <hip/hip_bf16.h>

// Problem constants: B=4, Q=256, K=256, H=512
#define B_ 4
#define Q_ 256
#define K_ 256
#define H_ 512
#define NEG (-1e9f)
// 2*log2(e): exp2(PRESCALE*x) = e^{2x}
#define PRESCALE 2.885390081777927f

typedef _Float16 half8 __attribute__((ext_vector_type(8)));
typedef float    f32x4 __attribute__((ext_vector_type(4)));

// ---------------------------------------------------------------------------
// Kernel 1: f16 MFMA projection GEMM + EXP epilogue.
//   z=0: Eq[b][q][h]  = exp2(PRESCALE * (query@Wq))   row-major
//   z=1: EkT[b][h][k] = exp2(PRESCALE * (key@Wk))     transposed output
// 64-row x 32-col tile, K-step 64, 512 thr (8 waves), grid (32,16) = 512
// blocks -> 2 blocks/CU. Double-buffered LDS + 2-DEEP register prefetch:
// loads for chunk i+2 are issued at iter i, consumed (ds_write) at iter i+2
// top -> a full iteration (~400 cyc) covers L2/HBM latency. ds_write reads
// its source regs at issue, so the set can be reloaded right after.
// Wave split (z-parameterized, z=1 swaps mfma operands):
//   z=0: A=X rows (aStrip=wave>>1, 4x16), B=W cols (bStrip=wave&1, 2x16)
//   z=1: A=W cols (aStrip=wave&1, 2x16),  B=X rows (bStrip=wave>>1, 4x16)
// Wl slab padded to 264 f16 (528B, %128=16) -> kgl groups hit different banks.
// Masked key tiles (k0 >= valid_len[b]) skipped.
// ---------------------------------------------------------------------------
__global__ __launch_bounds__(512) void proj_kernel(
    const float* __restrict__ Xq, const float* __restrict__ Xk,
    const float* __restrict__ Wq, const float* __restrict__ Wk,
    float* __restrict__ Eq, float* __restrict__ EkT,
    const int* __restrict__ vlen)
{
    const int bx   = blockIdx.x;          // 0..31
    const int z    = bx >> 4;             // 0 = q, 1 = k
    const int row0 = (bx & 15) * 64;      // X row base (q-row or b*256+k)
    const int bb   = row0 >> 8;
    const int k0   = row0 & 255;
    if (z && k0 >= vlen[bb]) return;      // masked kp cols never read downstream

    const float* X = z ? Xk : Xq;
    const float* W = z ? Wk : Wq;

    __shared__ _Float16 Xl[2][8 * 520];   // [buf][slab][row(pad65)][8]
    __shared__ _Float16 Wl[2][8 * 264];   // [buf][slab][col(pad33)][8]

    const int col0 = blockIdx.y * 32;     // W col base (= h base)
    const int t    = threadIdx.x;
    const int lane = t & 63;
    const int wave = t >> 6;              // 0..7
    const int m    = lane & 15;
    const int kgl  = lane >> 4;           // frag k-group 0..3

    const int aStrip = z ? (wave & 1) : (wave >> 1);
    const int bStrip = z ? (wave >> 1) : (wave & 1);

    // staging maps (per K-step-64 chunk)
    const int xr  = t >> 3;               // X row 0..63
    const int xg  = t & 7;                // X k-group 0..7
    const int wc  = t & 31;               // W col 0..31   (t < 256 only)
    const int wg  = (t >> 5) & 7;         // W k-group 0..7
    const bool doW = (t < 256);

    f32x4 acc = {};

    // 2-deep prefetch register sets
    float4 xa[2], xb[2];
    float  wr[2][8];
    #pragma unroll
    for (int s = 0; s < 2; ++s) {
        const int kk = s * 64;
        xa[s] = *(const float4*)&X[(size_t)(row0 + xr) * H_ + kk + xg * 8];
        xb[s] = *(const float4*)&X[(size_t)(row0 + xr) * H_ + kk + xg * 8 + 4];
        if (doW) {
            #pragma unroll
            for (int i = 0; i < 8; ++i)
                wr[s][i] = W[(size_t)(kk + wg * 8 + i) * H_ + col0 + wc];
        }
    }

    for (int it = 0; it < 8; ++it) {
        const int s = it & 1;
        // write chunk 'it' (set s) to LDS buf s
        {
            half8 hx;
            hx[0] = (_Float16)xa[s].x; hx[1] = (_Float16)xa[s].y;
            hx[2] = (_Float16)xa[s].z; hx[3] = (_Float16)xa[s].w;
            hx[4] = (_Float16)xb[s].x; hx[5] = (_Float16)xb[s].y;
            hx[6] = (_Float16)xb[s].z; hx[7] = (_Float16)xb[s].w;
            *(half8*)&Xl[s][xg * 520 + xr * 8] = hx;
            if (doW) {
                half8 hw;
                #pragma unroll
                for (int i = 0; i < 8; ++i) hw[i] = (_Float16)wr[s][i];
                *(half8*)&Wl[s][wg * 264 + wc * 8] = hw;
            }
        }
        __syncthreads();
        if (it + 2 < 8) {                 // issue chunk it+2 into set s
            const int kk = (it + 2) * 64;
            xa[s] = *(const float4*)&X[(size_t)(row0 + xr) * H_ + kk + xg * 8];
            xb[s] = *(const float4*)&X[(size_t)(row0 + xr) * H_ + kk + xg * 8 + 4];
            if (doW) {
                #pragma unroll
                for (int i = 0; i < 8; ++i)
                    wr[s][i] = W[(size_t)(kk + wg * 8 + i) * H_ + col0 + wc];
            }
        }
        // compute on buf s
        #pragma unroll
        for (int ks = 0; ks < 2; ++ks) {
            const int slab = ks * 4 + kgl;
            const half8 xf = *(const half8*)&Xl[s][slab * 520 + ((z ? bStrip : aStrip) * 16 + m) * 8];
            const half8 wf = *(const half8*)&Wl[s][slab * 264 + ((z ? aStrip : bStrip) * 16 + m) * 8];
            const half8 af = z ? wf : xf;
            const half8 bf = z ? xf : wf;
            acc = __builtin_amdgcn_mfma_f32_16x16x32_f16(af, bf, acc, 0, 0, 0);
        }
    }

    // epilogue: exp2(PRESCALE * acc); C/D: col = lane&15, row = (lane>>4)*4+r
    const int rsub = kgl * 4;
    if (!z) {
        const int gcol = col0 + bStrip * 16 + m;              // h
        #pragma unroll
        for (int r = 0; r < 4; ++r)
            Eq[(size_t)(row0 + aStrip * 16 + rsub + r) * H_ + gcol] =
                __builtin_amdgcn_exp2f(acc[r] * PRESCALE);
    } else {
        const int gk = k0 + bStrip * 16 + m;                  // k (coalesced)
        #pragma unroll
        for (int r = 0; r < 4; ++r)
            EkT[((size_t)bb * H_ + col0 + aStrip * 16 + rsub + r) * K_ + gk] =
                __builtin_amdgcn_exp2f(acc[r] * PRESCALE);
    }
}

// ---------------------------------------------------------------------------
// Kernel 2: fused scores -> masked softmax -> context.  TQ = 4 q-rows/block.
// grid = (Q/4, B) = (64, 4) = 256 blocks, 512 thr (8 waves).
// Score: wave w owns k-band [32w,+32), whole-wave skip if >= valid.
//   thread owns 4 q x 4 k, h-slice {ho+8s}; Ek b128 global, 2-deep prefetch;
//   eqh2 packed [ho][s][qi]; acc = fma(wm, rcp(fma(eq,ek,1)), .).
// Softmax: waves 0..3. Context: wave w owns its 32-k band, V loads 1-deep
//   prefetched, 3-level LDS tree reduce.
// ---------------------------------------------------------------------------
__global__ __launch_bounds__(512) void fused_attn(
    const float* __restrict__ Eq, const float* __restrict__ EkT,
    const float* __restrict__ value, const int* __restrict__ vlen,
    const float* __restrict__ wv, float* __restrict__ out)
{
    const int qt = blockIdx.x;        // 0..63
    const int b  = blockIdx.y;        // 0..3
    const int q0 = qt * 4;
    const int t    = threadIdx.x;
    const int wave = t >> 6;          // 0..7
    const int lane = t & 63;

    __shared__ float eqh2[8 * 260];   // [ho][s*4+qi], 8.3 KB
    __shared__ float wm2[8 * 68];     // [ho][s], 2.2 KB  (-2 * wv)
    __shared__ float sc[4][K_];       // 4 KB
    __shared__ float ctxp[4][4][H_];  // 32 KB reduce scratch

    const int valid = vlen[b];

    // ---- one-time staging: eq (repacked, 4 q rows) + wm (repacked) ----
    {
        const int qi = t >> 7, p4 = (t & 127) * 4;
        const float4 v = *(const float4*)&Eq[((size_t)b * Q_ + q0 + qi) * H_ + p4];
        const float vv[4] = {v.x, v.y, v.z, v.w};
        const int sbase = (p4 >> 3) * 4;
        #pragma unroll
        for (int j = 0; j < 4; ++j)
            eqh2[((p4 & 7) + j) * 260 + sbase + qi] = vv[j];
        if (t < 128) {
            const float4 w = *(const float4*)&wv[t * 4];
            const float ww[4] = {w.x, w.y, w.z, w.w};
            #pragma unroll
            for (int j = 0; j < 4; ++j) {
                const int h = t * 4 + j;
                wm2[(h & 7) * 68 + (h >> 3)] = -2.f * ww[j];
            }
        }
    }
    __syncthreads();

    // ---- score phase ----
    const int band = wave * 32;
    const int ho   = lane >> 3;       // h offset 0..7
    const int kg   = lane & 7;        // k group 0..7
    const int kq   = band + kg * 4;   // this thread's first k

    if (band < valid) {
        const float* ekp = EkT + ((size_t)b * H_ + ho) * K_ + kq;
        float acc0[4] = {}, acc1[4] = {}, acc2[4] = {}, acc3[4] = {};
        float4 pe[4], n1[4], n2[4];
        #pragma unroll
        for (int p = 0; p < 4; ++p)
            pe[p] = *(const float4*)(ekp + (size_t)p * 8 * K_);
        #pragma unroll
        for (int p = 0; p < 4; ++p)
            n1[p] = *(const float4*)(ekp + (size_t)(4 + p) * 8 * K_);

        for (int g = 0; g < 16; ++g) {        // 16 groups x 4 h-steps
            if (g < 14) {
                #pragma unroll
                for (int p = 0; p < 4; ++p)
                    n2[p] = *(const float4*)(ekp + (size_t)((g + 2) * 4 + p) * 8 * K_);
            }
            const float4 wv4 = *(const float4*)&wm2[ho * 68 + g * 4];
            const float wmp[4] = {wv4.x, wv4.y, wv4.z, wv4.w};
            #pragma unroll
            for (int p = 0; p < 4; ++p) {
                const float4 eq4 = *(const float4*)&eqh2[ho * 260 + (g * 4 + p) * 4];
                const float ek4[4] = {pe[p].x, pe[p].y, pe[p].z, pe[p].w};
                #pragma unroll
                for (int j = 0; j < 4; ++j) {
                    const float g0 = __builtin_fmaf(eq4.x, ek4[j], 1.0f);
                    acc0[j] = __builtin_fmaf(wmp[p], __builtin_amdgcn_rcpf(g0), acc0[j]);
                    const float g1 = __builtin_fmaf(eq4.y, ek4[j], 1.0f);
                    acc1[j] = __builtin_fmaf(wmp[p], __builtin_amdgcn_rcpf(g1), acc1[j]);
                    const float g2 = __builtin_fmaf(eq4.z, ek4[j], 1.0f);
                    acc2[j] = __builtin_fmaf(wmp[p], __builtin_amdgcn_rcpf(g2), acc2[j]);
                    const float g3 = __builtin_fmaf(eq4.w, ek4[j], 1.0f);
                    acc3[j] = __builtin_fmaf(wmp[p], __builtin_amdgcn_rcpf(g3), acc3[j]);
                }
            }
            #pragma unroll
            for (int p = 0; p < 4; ++p) { pe[p] = n1[p]; n1[p] = n2[p]; }
        }
        // combine h-partials across ho groups (lane bits 3..5)
        #pragma unroll
        for (int d = 8; d < 64; d <<= 1) {
            #pragma unroll
            for (int j = 0; j < 4; ++j) {
                acc0[j] += __shfl_xor(acc0[j], d);
                acc1[j] += __shfl_xor(acc1[j], d);
                acc2[j] += __shfl_xor(acc2[j], d);
                acc3[j] += __shfl_xor(acc3[j], d);
            }
        }
        if (ho == 0) {
            *(float4*)&sc[0][kq] = make_float4(acc0[0], acc0[1], acc0[2], acc0[3]);
            *(float4*)&sc[1][kq] = make_float4(acc1[0], acc1[1], acc1[2], acc1[3]);
            *(float4*)&sc[2][kq] = make_float4(acc2[0], acc2[1], acc2[2], acc2[3]);
            *(float4*)&sc[3][kq] = make_float4(acc3[0], acc3[1], acc3[2], acc3[3]);
        }
    }
    __syncthreads();

    // ---- masked softmax (waves 0..3; row = wave) ----
    if (wave < 4) {
        const int q = wave;
        if (valid == 0) {
            #pragma unroll
            for (int j = 0; j < 4; ++j) sc[q][lane + 64 * j] = 1.0f / K_;
        } else {
            float sv[4], mx = -3e38f;
            #pragma unroll
            for (int j = 0; j < 4; ++j) {
                const int kk = lane + 64 * j;
                const float s = (kk < valid) ? sc[q][kk] : NEG;
                sv[j] = s;
                mx = fmaxf(mx, s);
            }
            #pragma unroll
            for (int d = 32; d; d >>= 1) mx = fmaxf(mx, __shfl_xor(mx, d));
            float ev[4], sum = 0.f;
            #pragma unroll
            for (int j = 0; j < 4; ++j) { ev[j] = __expf(sv[j] - mx); sum += ev[j]; }
            #pragma unroll
            for (int d = 32; d; d >>= 1) sum += __shfl_xor(sum, d);
            const float inv = 1.0f / sum;
            #pragma unroll
            for (int j = 0; j < 4; ++j) sc[q][lane + 64 * j] = ev[j] * inv;
        }
    }
    __syncthreads();

    // ---- context: wave w owns k in [32w, 32w+32), 4 q rows, V prefetched ----
    const int klim = (valid == 0) ? K_ : valid;
    const int kb   = wave * 32;
    const int kend = min(32, klim - kb);
    const int h0   = lane * 8;

    float c[4][8] = {};
    float4 cv0, cv1;
    if (kend > 0) {
        const float4* vp = (const float4*)&value[((size_t)b * K_ + kb) * H_ + h0];
        cv0 = vp[0]; cv1 = vp[1];
    }
    for (int kc = 0; kc < kend; ++kc) {
        const int kk = kb + kc;
        float4 nv0, nv1;
        if (kc + 1 < kend) {
            const float4* vp = (const float4*)&value[((size_t)b * K_ + kk + 1) * H_ + h0];
            nv0 = vp[0]; nv1 = vp[1];
        }
        const float vr[8] = {cv0.x, cv0.y, cv0.z, cv0.w, cv1.x, cv1.y, cv1.z, cv1.w};
        const float a0 = sc[0][kk], a1 = sc[1][kk], a2 = sc[2][kk], a3 = sc[3][kk];
        #pragma unroll
        for (int j = 0; j < 8; ++j) {
            c[0][j] = __builtin_fmaf(a0, vr[j], c[0][j]);
            c[1][j] = __builtin_fmaf(a1, vr[j], c[1][j]);
            c[2][j] = __builtin_fmaf(a2, vr[j], c[2][j]);
            c[3][j] = __builtin_fmaf(a3, vr[j], c[3][j]);
        }
        cv0 = nv0; cv1 = nv1;
    }

    // 3-level tree reduce over 8 waves (4 q rows)
    #define PARK(s)                                                           \
        do {                                                                  \
            _Pragma("unroll")                                                 \
            for (int qi = 0; qi < 4; ++qi) {                                  \
                float* d = &ctxp[s][qi][h0];                                  \
                ((float4*)d)[0] = make_float4(c[qi][0], c[qi][1], c[qi][2], c[qi][3]); \
                ((float4*)d)[1] = make_float4(c[qi][4], c[qi][5], c[qi][6], c[qi][7]); \
            }                                                                 \
        } while (0)
    #define FOLD(s)                                                           \
        do {                                                                  \
            _Pragma("unroll")                                                 \
            for (int qi = 0; qi < 4; ++qi) {                                  \
                const float* d = &ctxp[s][qi][h0];                            \
                _Pragma("unroll")                                             \
                for (int j = 0; j < 8; ++j) c[qi][j] += d[j];                 \
            }                                                                 \
        } while (0)

    if (wave >= 4) PARK(wave - 4);
    __syncthreads();
    if (wave < 4) FOLD(wave);
    __syncthreads();
    if (wave == 2 || wave == 3) PARK(wave - 2);
    __syncthreads();
    if (wave < 2) FOLD(wave);
    __syncthreads();
    if (wave == 1) PARK(1);
    __syncthreads();
    if (wave == 0) {
        FOLD(1);
        #pragma unroll
        for (int qi = 0; qi < 4; ++qi) {
            float* o = &out[((size_t)b * Q_ + q0 + qi) * H_ + h0];
            ((float4*)o)[0] = make_float4(c[qi][0], c[qi][1], c[qi][2], c[qi][3]);
            ((float4*)o)[1] = make_float4(c[qi][4], c[qi][5], c[qi][6], c[qi][7]);
        }
    }
    #undef PARK
    #undef FOLD
}

// ---------------------------------------------------------------------------
extern "C" void kernel_launch(void* const* d_in, const int* in_sizes, int n_in,
                              void* d_out, int out_size, void* d_ws, size_t ws_size,
                              hipStream_t stream)
{
    const float* query = (const float*)d_in[0];
    const float* key   = (const float*)d_in[1];
    const float* value = (const float*)d_in[2];
    const int*   vlen  = (const int*)  d_in[3];
    const float* Wq    = (const float*)d_in[4];
    const float* Wk    = (const float*)d_in[5];
    const float* wv    = (const float*)d_in[6];
    float*       outp  = (float*)d_out;

    float* EqBuf  = (float*)d_ws;                 // [B*Q, H] = 2 MB (e^{2q'})
    float* EkTBuf = EqBuf + (size_t)B_ * Q_ * H_; // [B, H, K] = 2 MB (e^{2k'}, transposed)

    dim3 g1(32, 16);                              // 512 blocks, 512 threads
    proj_kernel<<<g1, 512, 0, stream>>>(query, key, Wq, Wk, EqBuf, EkTBuf, vlen);

    dim3 g2(Q_ / 4, B_);                          // (64, 4), 512 threads
    fused_attn<<<g2, 512, 0, stream>>>(EqBuf, EkTBuf, value, vlen, wv, outp);
}